// Round 5
// baseline (774.936 us; speedup 1.0000x reference)
//
#include <hip/hip_runtime.h>
#include <hip/hip_bf16.h>

#define HDD 64
#define NH 16
#define SEQ 2048
#define DM 1024
#define BB 4

using bf16x8 = __attribute__((ext_vector_type(8))) short;
using floatx4 = __attribute__((ext_vector_type(4))) float;

__device__ __forceinline__ short f2bf(float f) {
    __hip_bfloat16 h = __float2bfloat16(f);
    union { __hip_bfloat16 h; short s; } c;
    c.h = h;
    return c.s;
}

// Stage 8 contiguous fp32 elements from global into LDS as bf16.
__device__ __forceinline__ void stage8f(short* dst, const float* s) {
    float4 a = *(const float4*)s;
    float4 b = *(const float4*)(s + 4);
    bf16x8 r;
    r[0] = f2bf(a.x); r[1] = f2bf(a.y); r[2] = f2bf(a.z); r[3] = f2bf(a.w);
    r[4] = f2bf(b.x); r[5] = f2bf(b.y); r[6] = f2bf(b.z); r[7] = f2bf(b.w);
    *(bf16x8*)dst = r;
}

// ---------------------------------------------------------------------------
// QKV projection: Y = X @ W^T + b (fp32 in, bf16 MFMA).
// z=0: Q, pre-scaled by 1/sqrt(HD)=0.125 (exact exponent shift in bf16),
//      written head-split [B,H,S,HD].
// z=1: K, written head-split [B,H,S,HD].
// z=2: V, written TRANSPOSED head-split [B,H,HD,S] so attention can load
//      PV B-fragments (kv-contiguous) straight from global.
// ---------------------------------------------------------------------------
__global__ __launch_bounds__(256) void proj_kernel(
    const float* __restrict__ q, const float* __restrict__ k, const float* __restrict__ v,
    const float* __restrict__ wq, const float* __restrict__ bq,
    const float* __restrict__ wk, const float* __restrict__ bk,
    const float* __restrict__ wv, const float* __restrict__ bv,
    short* __restrict__ Qh, short* __restrict__ Kh, short* __restrict__ VhT)
{
    const int z = blockIdx.z;
    const float* X  = (z == 0) ? q  : (z == 1) ? k  : v;
    const float* W  = (z == 0) ? wq : (z == 1) ? wk : wv;
    const float* Bp = (z == 0) ? bq : (z == 1) ? bk : bv;

    const int m0 = blockIdx.x * 128;
    const int n0 = blockIdx.y * 128;
    const int tid = threadIdx.x;
    const int w = tid >> 6, lane = tid & 63, lc = lane & 15, lq = lane >> 4;
    const int wm = w >> 1, wn = w & 1;

    __shared__ alignas(16) short As[128 * 40];
    __shared__ alignas(16) short Bs[128 * 40];

    floatx4 acc[4][4];
#pragma unroll
    for (int i = 0; i < 4; i++)
#pragma unroll
        for (int j = 0; j < 4; j++) acc[i][j] = floatx4{0.f, 0.f, 0.f, 0.f};

    for (int kt = 0; kt < DM / 32; ++kt) {
        __syncthreads();
#pragma unroll
        for (int c = 0; c < 2; ++c) {
            int chunk = c * 256 + tid;
            int row = chunk >> 2;
            int col = (chunk & 3) * 8;
            stage8f(As + row * 40 + col, X + (size_t)(m0 + row) * DM + kt * 32 + col);
            stage8f(Bs + row * 40 + col, W + (size_t)(n0 + row) * DM + kt * 32 + col);
        }
        __syncthreads();

        bf16x8 aF[4], bF[4];
#pragma unroll
        for (int i = 0; i < 4; i++)
            aF[i] = *(const bf16x8*)(As + (wm * 64 + i * 16 + lc) * 40 + lq * 8);
#pragma unroll
        for (int j = 0; j < 4; j++)
            bF[j] = *(const bf16x8*)(Bs + (wn * 64 + j * 16 + lc) * 40 + lq * 8);
#pragma unroll
        for (int i = 0; i < 4; i++)
#pragma unroll
            for (int j = 0; j < 4; j++)
                acc[i][j] = __builtin_amdgcn_mfma_f32_16x16x32_bf16(aF[i], bF[j], acc[i][j], 0, 0, 0);
    }

    const float scale = (z == 0) ? 0.125f : 1.0f;
#pragma unroll
    for (int j = 0; j < 4; j++) {
        int n = n0 + wn * 64 + j * 16 + lc;
        float bias = Bp[n];
        int h = n >> 6, hd = n & 63;
#pragma unroll
        for (int i = 0; i < 4; i++) {
#pragma unroll
            for (int r = 0; r < 4; r++) {
                int m = m0 + wm * 64 + i * 16 + lq * 4 + r;
                int b = m >> 11, s = m & 2047;
                float val = (acc[i][j][r] + bias) * scale;
                if (z == 2) {
                    // V^T: [B,H,HD,S]
                    VhT[(((size_t)(b * NH + h)) * HDD + hd) * SEQ + s] = f2bf(val);
                } else {
                    short* Dst = (z == 0) ? Qh : Kh;
                    Dst[(((size_t)(b * NH + h)) * SEQ + s) * HDD + hd] = f2bf(val);
                }
            }
        }
    }
}

// ---------------------------------------------------------------------------
// Flash attention, barrier-free: one block = (b,h) x 64 q-rows, each wave
// owns 16 q-rows. K and V^T fragments load straight from global (L2-resident:
// 512 KB/head shared by 32 q-blocks). K loads issued first, V second ->
// QK waits vmcnt(8) while V stays in flight through the softmax VALU.
// Only LDS use: per-wave P scratch (C->A layout transform), stride 68.
// ---------------------------------------------------------------------------
__global__ __launch_bounds__(256) void attn_kernel(
    const short* __restrict__ Qh, const short* __restrict__ Kh,
    const short* __restrict__ VhT, float* __restrict__ ctxout)
{
    const int bh = blockIdx.y;
    const int tid = threadIdx.x;
    const int w = tid >> 6, lane = tid & 63, lc = lane & 15, lq = lane >> 4;
    const int qbase = blockIdx.x * 64 + w * 16;

    const short* Qp = Qh  + (size_t)bh * SEQ * HDD;
    const short* Kp = Kh  + (size_t)bh * SEQ * HDD;
    const short* Vp = VhT + (size_t)bh * HDD * SEQ;   // [d][s]

    __shared__ alignas(16) short Pl[4][16 * 68];   // per-wave P scratch [q][kv]

    bf16x8 aQ[2];
#pragma unroll
    for (int f = 0; f < 2; ++f)
        aQ[f] = *(const bf16x8*)(Qp + (size_t)(qbase + lc) * HDD + f * 32 + lq * 8);

    float mOld[4], lSum[4];
    floatx4 accO[4];
#pragma unroll
    for (int r = 0; r < 4; r++) { mOld[r] = -1e30f; lSum[r] = 0.f; }
#pragma unroll
    for (int dt = 0; dt < 4; dt++) accO[dt] = floatx4{0.f, 0.f, 0.f, 0.f};

    for (int kt = 0; kt < SEQ / 64; ++kt) {
        const int kv0 = kt * 64;

        // issue K loads first (consumed by QK), then V (consumed after softmax)
        bf16x8 bK[8], bV[8];
#pragma unroll
        for (int nt = 0; nt < 4; nt++)
#pragma unroll
            for (int f = 0; f < 2; f++)
                bK[nt * 2 + f] = *(const bf16x8*)(Kp + (size_t)(kv0 + nt * 16 + lc) * HDD + f * 32 + lq * 8);
#pragma unroll
        for (int dt = 0; dt < 4; dt++)
#pragma unroll
            for (int f = 0; f < 2; f++)
                bV[dt * 2 + f] = *(const bf16x8*)(Vp + (size_t)(dt * 16 + lc) * SEQ + kv0 + f * 32 + lq * 8);

        // scores (Q pre-scaled by 0.125 at projection time)
        floatx4 sc[4];
#pragma unroll
        for (int nt = 0; nt < 4; nt++) {
            floatx4 sv = floatx4{0.f, 0.f, 0.f, 0.f};
            sv = __builtin_amdgcn_mfma_f32_16x16x32_bf16(aQ[0], bK[nt * 2 + 0], sv, 0, 0, 0);
            sv = __builtin_amdgcn_mfma_f32_16x16x32_bf16(aQ[1], bK[nt * 2 + 1], sv, 0, 0, 0);
            sc[nt] = sv;
        }

        // online softmax (per q-row = (lq, r); kv over 16 lanes x 4 tiles)
        float mNew[4], alpha[4], rsum[4];
#pragma unroll
        for (int r = 0; r < 4; r++) {
            float mx = fmaxf(fmaxf(sc[0][r], sc[1][r]), fmaxf(sc[2][r], sc[3][r]));
#pragma unroll
            for (int off = 1; off < 16; off <<= 1)
                mx = fmaxf(mx, __shfl_xor(mx, off, 64));
            mNew[r] = fmaxf(mOld[r], mx);
            alpha[r] = __expf(mOld[r] - mNew[r]);
            rsum[r] = 0.f;
        }
#pragma unroll
        for (int nt = 0; nt < 4; nt++)
#pragma unroll
            for (int r = 0; r < 4; r++) {
                float p = __expf(sc[nt][r] - mNew[r]);
                sc[nt][r] = p;
                rsum[r] += p;
            }
#pragma unroll
        for (int r = 0; r < 4; r++) {
            float rs = rsum[r];
#pragma unroll
            for (int off = 1; off < 16; off <<= 1)
                rs += __shfl_xor(rs, off, 64);
            lSum[r] = lSum[r] * alpha[r] + rs;
            mOld[r] = mNew[r];
        }

        // P (C-layout) -> per-wave LDS; stride 68 = conflict-free scalar writes
#pragma unroll
        for (int nt = 0; nt < 4; nt++)
#pragma unroll
            for (int r = 0; r < 4; r++)
                Pl[w][(lq * 4 + r) * 68 + nt * 16 + lc] = f2bf(sc[nt][r]);

        // rescale O
#pragma unroll
        for (int dt = 0; dt < 4; dt++)
#pragma unroll
            for (int r = 0; r < 4; r++) accO[dt][r] *= alpha[r];

        // PV: A = P (A-layout read-back), B = V^T frags from global
#pragma unroll
        for (int f = 0; f < 2; f++) {
            bf16x8 aP = *(const bf16x8*)(&Pl[w][lc * 68 + f * 32 + lq * 8]);
#pragma unroll
            for (int dt = 0; dt < 4; dt++)
                accO[dt] = __builtin_amdgcn_mfma_f32_16x16x32_bf16(aP, bV[dt * 2 + f], accO[dt], 0, 0, 0);
        }
    }

    // epilogue: ctx[b,h,q,d] = O / l  (fp32)
#pragma unroll
    for (int dt = 0; dt < 4; dt++)
#pragma unroll
        for (int r = 0; r < 4; r++) {
            int qrow = qbase + lq * 4 + r;
            int d = dt * 16 + lc;
            ctxout[((size_t)bh * SEQ + qrow) * HDD + d] = accO[dt][r] / lSum[r];
        }
}

// ---------------------------------------------------------------------------
// Output projection: out = merged(ctx) @ Wo^T + bo. A gathered from the fp32
// ctx in d_out (head-split layout), out written fp32.
// ---------------------------------------------------------------------------
__global__ __launch_bounds__(256) void outproj_kernel(
    const float* __restrict__ ctxb, const float* __restrict__ wo,
    const float* __restrict__ bo, float* __restrict__ out)
{
    const int m0 = blockIdx.x * 128;
    const int n0 = blockIdx.y * 128;
    const int tid = threadIdx.x;
    const int w = tid >> 6, lane = tid & 63, lc = lane & 15, lq = lane >> 4;
    const int wm = w >> 1, wn = w & 1;

    __shared__ alignas(16) short As[128 * 40];
    __shared__ alignas(16) short Bs[128 * 40];

    floatx4 acc[4][4];
#pragma unroll
    for (int i = 0; i < 4; i++)
#pragma unroll
        for (int j = 0; j < 4; j++) acc[i][j] = floatx4{0.f, 0.f, 0.f, 0.f};

    for (int kt = 0; kt < DM / 32; ++kt) {
        __syncthreads();
#pragma unroll
        for (int c = 0; c < 2; ++c) {
            int chunk = c * 256 + tid;
            int row = chunk >> 2;
            int col = (chunk & 3) * 8;
            int m = m0 + row;
            int b = m >> 11, s = m & 2047;
            int kcol = kt * 32 + col;
            int h = kcol >> 6, hd = kcol & 63;
            stage8f(As + row * 40 + col,
                    ctxb + (((size_t)(b * NH + h)) * SEQ + s) * HDD + hd);
            stage8f(Bs + row * 40 + col, wo + (size_t)(n0 + row) * DM + kt * 32 + col);
        }
        __syncthreads();

        bf16x8 aF[4], bF[4];
#pragma unroll
        for (int i = 0; i < 4; i++)
            aF[i] = *(const bf16x8*)(As + (wm * 64 + i * 16 + lc) * 40 + lq * 8);
#pragma unroll
        for (int j = 0; j < 4; j++)
            bF[j] = *(const bf16x8*)(Bs + (wn * 64 + j * 16 + lc) * 40 + lq * 8);
#pragma unroll
        for (int i = 0; i < 4; i++)
#pragma unroll
            for (int j = 0; j < 4; j++)
                acc[i][j] = __builtin_amdgcn_mfma_f32_16x16x32_bf16(aF[i], bF[j], acc[i][j], 0, 0, 0);
    }

#pragma unroll
    for (int j = 0; j < 4; j++) {
        int n = n0 + wn * 64 + j * 16 + lc;
        float bias = bo[n];
#pragma unroll
        for (int i = 0; i < 4; i++) {
#pragma unroll
            for (int r = 0; r < 4; r++) {
                int m = m0 + wm * 64 + i * 16 + lq * 4 + r;
                out[(size_t)m * DM + n] = acc[i][j][r] + bias;
            }
        }
    }
}

extern "C" void kernel_launch(void* const* d_in, const int* in_sizes, int n_in,
                              void* d_out, int out_size, void* d_ws, size_t ws_size,
                              hipStream_t stream) {
    const float* q  = (const float*)d_in[0];
    const float* k  = (const float*)d_in[1];
    const float* v  = (const float*)d_in[2];
    const float* wq = (const float*)d_in[3];
    const float* bq = (const float*)d_in[4];
    const float* wk = (const float*)d_in[5];
    const float* bk = (const float*)d_in[6];
    const float* wv = (const float*)d_in[7];
    const float* bv = (const float*)d_in[8];
    const float* wo = (const float*)d_in[9];
    const float* bo = (const float*)d_in[10];

    float* out0 = (float*)d_out;                          // [B,S,D] fp32
    float* ctx  = out0 + (size_t)BB * SEQ * DM;           // [B,H,S,HD] fp32

    short* Qh  = (short*)d_ws;
    short* Kh  = Qh + (size_t)BB * NH * SEQ * HDD;
    short* VhT = Kh + (size_t)BB * NH * SEQ * HDD;        // [B,H,HD,S]

    proj_kernel<<<dim3(64, 8, 3), 256, 0, stream>>>(q, k, v, wq, bq, wk, bk, wv, bv, Qh, Kh, VhT);
    attn_kernel<<<dim3(32, 64), 256, 0, stream>>>(Qh, Kh, VhT, ctx);
    outproj_kernel<<<dim3(64, 8), 256, 0, stream>>>(ctx, wo, bo, out0);
}